// Round 6
// baseline (887.657 us; speedup 1.0000x reference)
//
#include <hip/hip_runtime.h>

#define T_     24
#define LAMDA_ 0.2f

// output layout (flat f32): outs[24,64,256] | cs[64,256] | las[24,64,32] | gas[24,64,256]
#define OFF_CS  393216
#define OFF_LAS 409600
#define OFF_GAS 458752

__device__ __forceinline__ float clamp15(float x){ return fminf(15.f, fmaxf(-15.f, x)); }
__device__ __forceinline__ float rcp_(float x){ return __builtin_amdgcn_rcpf(x); }

// ---------------------------------------------------------------------------
// R15: R14's spill tripwire fired (WRITE 47MB): at 1024thr the VGPR cap is 64
// PERIOD (confirmed R9-R14) -- wA/wB[9] (72 always-live regs) thrashed
// scratch. But the exchange protocol + 4x CU scaling + fused LSTM all proved
// out (passed, 47% VALUBusy). R15 = sibling split redesigned for <=64-VGPR
// EPHEMERAL demand everywhere (R12 discipline):
//  - A: stream Wih from L2 (no reg residency). 192 rows/block: 96 slots x
//    2 rows, 9 f4 in flight per jc fence (~45 regs peak). 18 f4/thread/step.
//  - B: 64 threads, LSTM from gbuf + publish own c quarter (exchange #1).
//  - C: replicated 16-lane-team dots (R14 code, proven) -> pair coeffs.
//  - D: s_g SPLIT by s-quarter (768 thr: own 64 s x 12 og x 2 o) +
//    s_l on 256 thr (3 o each, 8-lane shfl reduce). ~4x less D work.
//  - exchange #2: raw s_g quarters (stamp/spin, t-parity dbuf; ABA-safe:
//    two-exchange lockstep bounds sibling skew < 1 step).
//  - E: gas softmax reads 1 exchanged value per s; x-build as before.
//  - init: Eg computed only for own s-quarter (24x64): init work /3,
//    gs HBM 200->50MB, Eg LDS 24->6KB.
// Tripwires: WRITE>15MB = spill; hang = sync bug (revert to R12+fusion).
// ---------------------------------------------------------------------------
__global__ __launch_bounds__(1024, 4) void spat_kernel(
    const float* __restrict__ li,  const float* __restrict__ gi,
    const float* __restrict__ ls,  const float* __restrict__ gs,
    const float* __restrict__ dist,
    const float* __restrict__ la0, const float* __restrict__ ga0,
    const float* __restrict__ Wcl, const float* __restrict__ bcl,
    const float* __restrict__ Wll, const float* __restrict__ bll, const float* __restrict__ vl,
    const float* __restrict__ Wcg, const float* __restrict__ bcg,
    const float* __restrict__ Wlg, const float* __restrict__ blg, const float* __restrict__ vg,
    const float* __restrict__ Wih, const float* __restrict__ bih, const float* __restrict__ bhh,
    float* __restrict__ ws, float* __restrict__ out)
{
    __shared__ float Eg[1536];               // exp(2*hf_g[o][s_loc]), o<24, own 64 s
    __shared__ float El[800];                // exp(2*hf_l), idx l*25+o (full)
    __shared__ float outb[1536];             // h quarter   [t][64]
    __shared__ float gasb[1536];             // gas quarter [t][64]
    __shared__ float lasb[192];              // las quarter [t][8]
    __shared__ float csb[64];                // c quarter at t=23
    __shared__ __align__(16) union {
        float wcg[6144];                     // Wcg staging (init only)
        struct {
            float sgred[768];                // s_g partials [og][s_loc]
            float sgfull[256];               // exchanged raw s_g
            float cqf[256];                  // FULL c vector
            float xv[288];
            float gbuf[192];                 // gate sums (i|g|o x 64)
            float slg[32];
        } p;
    } U;
    __shared__ float dstf[256];
    __shared__ float bsum[192];              // bih+bhh for own gate rows
    __shared__ float bcf[48];                // bll|blg
    __shared__ __align__(16) float4 pl4[12], pg4[12];  // pair coeffs (A0,A1,B1,B2)
    __shared__ float vlf[24], vgf[24], cbuf[2];
    // shaping pad: LDS > 80KB -> exactly 1 WG/CU (even spread of the 256 WGs)
    __shared__ float ldspad[9216];

    const int bid = blockIdx.x;
    const int b = bid >> 2, K = bid & 3;     // batch, sibling index
    const int tid = threadIdx.x;

    float* wsb   = ws + (size_t)b * 1280;    // per-batch: c[2][256] | sg[2][256] | stamps
    int*   wst_c = (int*)(wsb + 1024);       // c stamps  [2 parity][4 K]
    int*   wst_g = wst_c + 8;                // sg stamps [2 parity][4 K]

    // keep-alive for ldspad (branch never taken)
    if (__builtin_expect((int)blockIdx.x == 0x7fffffff, 0)) {
        ldspad[tid] = bcg[0];
        out[0] = ldspad[tid ^ 1];
    }

    // ---- small init (before first barrier) ----
    if (tid < 256) dstf[tid] = dist[b*256 + tid];
    if (tid < 24)  { vlf[tid] = vl[tid]; vgf[tid] = vg[tid]; }
    if (tid < 48)  bcf[tid] = (tid < 24) ? bll[tid] : blg[tid - 24];
    if (tid < 192) {
        const int gate = tid >> 6, u = tid & 63;
        const int wrow = gate*256 + (gate ? 256 : 0) + K*64 + u;   // i:0 g:512 o:768
        bsum[tid] = bih[wrow] + bhh[wrow];
    }
    if (tid == 0)  { float s1 = 0.f; for (int d = 0; d < 24; d++) s1 += vl[d]; cbuf[0] = s1; }
    if (tid == 1)  { float s1 = 0.f; for (int d = 0; d < 24; d++) s1 += vg[d]; cbuf[1] = s1; }

    // ---- hf_g init, OWN s-quarter only: tid<768 -> (s_loc=tid&63, og=tid>>6),
    //      o in {og, og+12} ----
    const int s_loc = tid & 63, og = tid >> 6;   // og<12 for tid<768
    float acc_a = 0.f, acc_b = 0.f;
    if (tid < 768) { acc_a = bcg[og]; acc_b = bcg[og + 12]; }

    for (int hc = 0; hc < 3; hc++) {
        for (int k = tid; k < 6144; k += 1024) {
            const int o = k >> 8, r = k & 255;
            U.wcg[k] = Wcg[o*768 + hc*256 + r];
        }
        __syncthreads();
        if (tid < 768) {
            for (int cc = 0; cc < 8; cc++) {
                const int c = hc*8 + cc;
                const float4* gp = (const float4*)(gs + ((size_t)b*196608 + c*8192 + (K*64 + s_loc)*32));
#pragma unroll
                for (int h = 0; h < 2; h++) {
                    float gv[16];
#pragma unroll
                    for (int m = 0; m < 4; m++) {
                        const float4 g = gp[h*4 + m];
                        gv[4*m] = g.x; gv[4*m+1] = g.y; gv[4*m+2] = g.z; gv[4*m+3] = g.w;
                    }
                    const float4* wpa = (const float4*)(U.wcg + (og*256 + cc*32)) + h*4;
                    const float4* wpb = (const float4*)(U.wcg + ((og+12)*256 + cc*32)) + h*4;
                    float aa = acc_a, ab = acc_b;
#pragma unroll
                    for (int m = 0; m < 4; m++) {
                        const float4 wa = wpa[m], wb = wpb[m];
                        aa = fmaf(wa.x, gv[4*m],   aa); aa = fmaf(wa.y, gv[4*m+1], aa);
                        aa = fmaf(wa.z, gv[4*m+2], aa); aa = fmaf(wa.w, gv[4*m+3], aa);
                        ab = fmaf(wb.x, gv[4*m],   ab); ab = fmaf(wb.y, gv[4*m+1], ab);
                        ab = fmaf(wb.z, gv[4*m+2], ab); ab = fmaf(wb.w, gv[4*m+3], ab);
                    }
                    acc_a = aa; acc_b = ab;
                }
            }
        }
        __syncthreads();
    }
    if (tid < 768) {
        Eg[og*64 + s_loc]      = __expf(2.f*clamp15(acc_a));
        Eg[(og+12)*64 + s_loc] = __expf(2.f*clamp15(acc_b));
    }

    // ---- hf_l -> El (FULL, replicated; idx l*25+o) ----
    if (tid < 768) {
        const int o = tid >> 5, l = tid & 31;
        float a = bcl[o];
        for (int c = 0; c < 24; c++)
            a = fmaf(Wcl[o*24 + c], ls[b*768 + c*32 + l], a);
        El[l*25 + o] = __expf(2.f*clamp15(a));
    }

    // ---- x for t=0 ----
    if (tid < 288) {
        if (tid < 32) U.p.xv[tid] = la0[b*32 + tid] * li[b*32 + tid];
        else { const int ss = tid - 32; U.p.xv[tid] = ga0[b*256 + ss] * gi[b*256 + ss]; }
    }
    __syncthreads();

    const int u8 = tid & 7, slot = tid >> 3;   // A/C team layout

    for (int t = 0; t < T_; t++) {
        // prefetch next-step inputs (wave0: li, wave1: gi)
        float liN = 0.f;
        float giN0 = 0.f, giN1 = 0.f, giN2 = 0.f, giN3 = 0.f;
        if (t < T_ - 1) {
            if (tid < 32) liN = li[(t+1)*2048 + b*32 + tid];
            else if (tid >= 64 && tid < 128) {
                const int lane = tid - 64;
                giN0 = gi[(t+1)*16384 + b*256 + lane];
                giN1 = gi[(t+1)*16384 + b*256 + lane + 64];
                giN2 = gi[(t+1)*16384 + b*256 + lane + 128];
                giN3 = gi[(t+1)*16384 + b*256 + lane + 192];
            }
        }

        // ---- A: own 192 gate rows, 96 slots x 2 rows, Wih streamed ----
        if (tid < 768) {
            const int r0 = slot*2, r1 = r0 + 1;
            const int g0 = r0 >> 6, g1 = r1 >> 6;
            const int wrow0 = g0*256 + (g0 ? 256 : 0) + K*64 + (r0 & 63);
            const int wrow1 = g1*256 + (g1 ? 256 : 0) + K*64 + (r1 & 63);
            const float4* xp4 = (const float4*)U.p.xv;
            const float4* wb0 = (const float4*)(Wih + wrow0*288);
            const float4* wb1 = (const float4*)(Wih + wrow1*288);
            float ar0 = 0.f, ar1 = 0.f;
#pragma unroll 1
            for (int jc = 0; jc < 3; jc++) {
                const int base = jc*24 + u8;
                const float4 x0 = xp4[base], x1 = xp4[base+8], x2 = xp4[base+16];
                {
                    const float4 wa = wb0[base], wbq = wb0[base+8], wc = wb0[base+16];
                    float a_ = ar0;
                    a_ = fmaf(wa.x,x0.x,a_);  a_ = fmaf(wa.y,x0.y,a_);
                    a_ = fmaf(wa.z,x0.z,a_);  a_ = fmaf(wa.w,x0.w,a_);
                    a_ = fmaf(wbq.x,x1.x,a_); a_ = fmaf(wbq.y,x1.y,a_);
                    a_ = fmaf(wbq.z,x1.z,a_); a_ = fmaf(wbq.w,x1.w,a_);
                    a_ = fmaf(wc.x,x2.x,a_);  a_ = fmaf(wc.y,x2.y,a_);
                    a_ = fmaf(wc.z,x2.z,a_);  a_ = fmaf(wc.w,x2.w,a_);
                    ar0 = a_;
                }
                {
                    const float4 wa = wb1[base], wbq = wb1[base+8], wc = wb1[base+16];
                    float a_ = ar1;
                    a_ = fmaf(wa.x,x0.x,a_);  a_ = fmaf(wa.y,x0.y,a_);
                    a_ = fmaf(wa.z,x0.z,a_);  a_ = fmaf(wa.w,x0.w,a_);
                    a_ = fmaf(wbq.x,x1.x,a_); a_ = fmaf(wbq.y,x1.y,a_);
                    a_ = fmaf(wbq.z,x1.z,a_); a_ = fmaf(wbq.w,x1.w,a_);
                    a_ = fmaf(wc.x,x2.x,a_);  a_ = fmaf(wc.y,x2.y,a_);
                    a_ = fmaf(wc.z,x2.z,a_);  a_ = fmaf(wc.w,x2.w,a_);
                    ar1 = a_;
                }
                __builtin_amdgcn_sched_barrier(0);
            }
            ar0 += __shfl_xor(ar0, 1); ar0 += __shfl_xor(ar0, 2); ar0 += __shfl_xor(ar0, 4);
            ar1 += __shfl_xor(ar1, 1); ar1 += __shfl_xor(ar1, 2); ar1 += __shfl_xor(ar1, 4);
            if (u8 == 0) {
                U.p.gbuf[r0] = ar0 + bsum[r0];
                U.p.gbuf[r1] = ar1 + bsum[r1];
            }
        }
        __syncthreads();                              // #1

        // ---- B: LSTM for own 64 units; publish c quarter ----
        if (tid < 64) {
            const float ig = U.p.gbuf[tid], gg = U.p.gbuf[64 + tid], ot = U.p.gbuf[128 + tid];
            const float sig_i = rcp_(1.f + __expf(-ig));
            const float th_g  = 1.f - 2.f*rcp_(1.f + __expf(2.f*clamp15(gg)));
            const float c     = sig_i * th_g;
            const float sig_o = rcp_(1.f + __expf(-ot));
            const float th_c  = 1.f - 2.f*rcp_(1.f + __expf(2.f*c));
            const float h     = sig_o * th_c;
            U.p.cqf[K*64 + tid] = c;
            outb[t*64 + tid] = h;
            if (t == T_ - 1) csb[tid] = c;
            wsb[(t&1)*256 + K*64 + tid] = c;          // publish own quarter
        }
        __syncthreads();                              // #2 (c stores drained)

        // ---- exchange #1: stamp + pull 3 partner c quarters ----
        if (tid == 0)
            __hip_atomic_store(&wst_c[(t&1)*4 + K], t+1,
                               __ATOMIC_RELEASE, __HIP_MEMORY_SCOPE_AGENT);
        if (tid < 192) {
            const int pp = tid >> 6;
            const int P  = pp + (pp >= K ? 1 : 0);
            const int j  = tid & 63;
            while (__hip_atomic_load(&wst_c[(t&1)*4 + P],
                                     __ATOMIC_ACQUIRE, __HIP_MEMORY_SCOPE_AGENT) != t+1)
                __builtin_amdgcn_s_sleep(1);
            U.p.cqf[P*64 + j] =
                __hip_atomic_load(&wsb[(t&1)*256 + P*64 + j],
                                  __ATOMIC_RELAXED, __HIP_MEMORY_SCOPE_AGENT);
        }
        __syncthreads();                              // #3 (cqf full)

        // ---- C: 48 dots x 16-lane teams over full cqf; pair coeffs ----
        if (tid < 768) {
            const int dot = tid >> 4, l16 = tid & 15;
            const float* Wr = (dot < 24) ? (Wll + dot*256) : (Wlg + (dot - 24)*256);
            const float4* wp = (const float4*)Wr + l16*4;
            const float4* cp = (const float4*)U.p.cqf + l16*4;
            float a0 = 0.f, a1 = 0.f;
#pragma unroll
            for (int m = 0; m < 4; m += 2) {
                const float4 w0 = wp[m],   c0 = cp[m];
                const float4 w1 = wp[m+1], c1 = cp[m+1];
                a0 = fmaf(w0.x,c0.x,a0); a0 = fmaf(w0.y,c0.y,a0);
                a0 = fmaf(w0.z,c0.z,a0); a0 = fmaf(w0.w,c0.w,a0);
                a1 = fmaf(w1.x,c1.x,a1); a1 = fmaf(w1.y,c1.y,a1);
                a1 = fmaf(w1.z,c1.z,a1); a1 = fmaf(w1.w,c1.w,a1);
            }
            float a = a0 + a1;
            a += __shfl_xor(a, 1); a += __shfl_xor(a, 2);
            a += __shfl_xor(a, 4); a += __shfl_xor(a, 8);
            const float F  = __expf(2.f*clamp15(a + bcf[dot]));
            const float v  = (dot < 24) ? vlf[dot] : vgf[dot - 24];
            const float Fo = __shfl_xor(F, 16);        // partner team (dot^1)
            const float vo = (dot < 24) ? vlf[dot ^ 1] : vgf[(dot ^ 1) - 24];
            if ((tid & 31) == 0) {                     // lane 0 of even dot
                const float A0 = v + vo;
                const float A1 = fmaf(v, Fo, vo * F);
                const float B1 = F + Fo;
                const float B2 = F * Fo;
                const int P2 = dot >> 1;               // 0..23
                if (P2 < 12) pl4[P2]      = make_float4(A0, A1, B1, B2);
                else         pg4[P2 - 12] = make_float4(A0, A1, B1, B2);
            }
        }
        __syncthreads();                              // #4

        // ---- D: s_g partials for OWN s-quarter (tid<768: 2 o x 12 pairs)
        //      + s_l partials (tid>=768: 3 o x 12 pairs, 8-lane reduce) ----
        if (tid < 768) {
            const float za = Eg[og*64 + s_loc],      za2 = za*za;
            const float zb = Eg[(og+12)*64 + s_loc], zb2 = zb*zb;
            float a0 = 0.f;
#pragma unroll 4
            for (int p = 0; p < 12; p++) {
                const float4 q = pg4[p];
                const float na = fmaf(za, q.y, q.x);
                const float da = fmaf(za2, q.w, fmaf(za, q.z, 1.f));
                const float nb = fmaf(zb, q.y, q.x);
                const float db = fmaf(zb2, q.w, fmaf(zb, q.z, 1.f));
                a0 = fmaf(na, rcp_(da), a0);
                a0 = fmaf(nb, rcp_(db), a0);
            }
            U.p.sgred[og*64 + s_loc] = a0;
        } else {
            const int tid2 = tid - 768;
            const int l = tid2 >> 3, oo = tid2 & 7;
            float bsl = 0.f;
#pragma unroll
            for (int oc = 0; oc < 3; oc++) {
                const float E  = El[l*25 + oo + oc*8];
                const float E2 = E*E;
#pragma unroll 4
                for (int p = 0; p < 12; p++) {
                    const float4 q = pl4[p];
                    const float num = fmaf(E,  q.y, q.x);
                    const float den = fmaf(E2, q.w, fmaf(E, q.z, 1.f));
                    bsl = fmaf(num, rcp_(den), bsl);
                }
            }
            bsl += __shfl_xor(bsl, 1); bsl += __shfl_xor(bsl, 2); bsl += __shfl_xor(bsl, 4);
            if (oo == 0) U.p.slg[l] = bsl;
        }
        __syncthreads();                              // #5

        // ---- sg finalize + publish own quarter ----
        if (tid < 64) {
            float sq = 0.f;
#pragma unroll
            for (int g2 = 0; g2 < 12; g2++) sq += U.p.sgred[g2*64 + tid];
            U.p.sgfull[K*64 + tid] = sq;
            wsb[512 + (t&1)*256 + K*64 + tid] = sq;
        }
        __syncthreads();                              // #6 (sg stores drained)

        // ---- exchange #2: stamp + pull 3 partner sg quarters ----
        if (tid == 0)
            __hip_atomic_store(&wst_g[(t&1)*4 + K], t+1,
                               __ATOMIC_RELEASE, __HIP_MEMORY_SCOPE_AGENT);
        if (tid < 192) {
            const int pp = tid >> 6;
            const int P  = pp + (pp >= K ? 1 : 0);
            const int j  = tid & 63;
            while (__hip_atomic_load(&wst_g[(t&1)*4 + P],
                                     __ATOMIC_ACQUIRE, __HIP_MEMORY_SCOPE_AGENT) != t+1)
                __builtin_amdgcn_s_sleep(1);
            U.p.sgfull[P*64 + j] =
                __hip_atomic_load(&wsb[512 + (t&1)*256 + P*64 + j],
                                  __ATOMIC_RELAXED, __HIP_MEMORY_SCOPE_AGENT);
        }
        __syncthreads();                              // #7 (sgfull complete)

        // ---- E: softmaxes (replicated, identical inputs) + x-build ----
        if (tid < 32) {                       // wave0: s_l softmax
            const float sv = 24.f*cbuf[0] - 2.f*U.p.slg[tid];
            float m = sv;
#pragma unroll
            for (int mk = 16; mk >= 1; mk >>= 1) m = fmaxf(m, __shfl_xor(m, mk));
            const float e = __expf(sv - m);
            float ss = e;
#pragma unroll
            for (int mk = 16; mk >= 1; mk >>= 1) ss += __shfl_xor(ss, mk);
            const float r = e * rcp_(ss);
            if ((tid >> 3) == K) lasb[t*8 + (tid & 7)] = r;
            if (t < T_ - 1) U.p.xv[tid] = r * liN;
        } else if (tid >= 64 && tid < 128) {  // wave1: s_g softmax, 4 s/lane
            const int lane = tid - 64;
            const float base = 24.f*cbuf[1];
            const float vv0 = (1.f-LAMDA_)*(base - 2.f*U.p.sgfull[lane])     + LAMDA_*dstf[lane];
            const float vv1 = (1.f-LAMDA_)*(base - 2.f*U.p.sgfull[lane+64])  + LAMDA_*dstf[lane+64];
            const float vv2 = (1.f-LAMDA_)*(base - 2.f*U.p.sgfull[lane+128]) + LAMDA_*dstf[lane+128];
            const float vv3 = (1.f-LAMDA_)*(base - 2.f*U.p.sgfull[lane+192]) + LAMDA_*dstf[lane+192];
            float m = fmaxf(fmaxf(vv0, vv1), fmaxf(vv2, vv3));
#pragma unroll
            for (int mk = 32; mk >= 1; mk >>= 1) m = fmaxf(m, __shfl_xor(m, mk));
            const float e0 = __expf(vv0 - m), e1 = __expf(vv1 - m);
            const float e2 = __expf(vv2 - m), e3 = __expf(vv3 - m);
            float ss = (e0 + e1) + (e2 + e3);
#pragma unroll
            for (int mk = 32; mk >= 1; mk >>= 1) ss += __shfl_xor(ss, mk);
            const float inv = rcp_(ss);
            const float r0 = e0*inv, r1 = e1*inv, r2 = e2*inv, r3 = e3*inv;
            const float rK = (K == 0) ? r0 : (K == 1) ? r1 : (K == 2) ? r2 : r3;
            gasb[t*64 + lane] = rK;                   // own s-quarter
            if (t < T_ - 1) {
                U.p.xv[32+lane]     = r0 * giN0;
                U.p.xv[32+lane+64]  = r1 * giN1;
                U.p.xv[32+lane+128] = r2 * giN2;
                U.p.xv[32+lane+192] = r3 * giN3;
            }
        }
        __syncthreads();                              // #8
    }

    // ---- final flush: quarter buffers -> global ----
    for (int k = tid; k < 1536; k += 1024) {
        const int tt = k >> 6, j = k & 63;
        out[tt*16384 + b*256 + K*64 + j]           = outb[k];
        out[OFF_GAS + tt*16384 + b*256 + K*64 + j] = gasb[k];
    }
    if (tid < 192) {
        const int tt = tid >> 3, j = tid & 7;
        out[OFF_LAS + tt*2048 + b*32 + K*8 + j] = lasb[tid];
    }
    if (tid < 64) out[OFF_CS + b*256 + K*64 + tid] = csb[tid];
}

extern "C" void kernel_launch(void* const* d_in, const int* in_sizes, int n_in,
                              void* d_out, int out_size, void* d_ws, size_t ws_size,
                              hipStream_t stream)
{
    const float* li   = (const float*)d_in[0];
    const float* gi   = (const float*)d_in[1];
    const float* ls   = (const float*)d_in[2];
    const float* gs   = (const float*)d_in[3];
    const float* dist = (const float*)d_in[4];
    const float* la0  = (const float*)d_in[5];
    const float* ga0  = (const float*)d_in[6];
    const float* Wcl  = (const float*)d_in[7];
    const float* bcl  = (const float*)d_in[8];
    const float* Wll  = (const float*)d_in[9];
    const float* bll  = (const float*)d_in[10];
    const float* vl   = (const float*)d_in[11];
    const float* Wcg  = (const float*)d_in[12];
    const float* bcg  = (const float*)d_in[13];
    const float* Wlg  = (const float*)d_in[14];
    const float* blg  = (const float*)d_in[15];
    const float* vg   = (const float*)d_in[16];
    const float* Wih  = (const float*)d_in[17];
    const float* bih  = (const float*)d_in[18];
    const float* bhh  = (const float*)d_in[19];

    // zero exchange workspace (stamps must start 0). 64 x 1280 floats = 320KB.
    hipMemsetAsync(d_ws, 0, 64 * 1280 * sizeof(float), stream);

    spat_kernel<<<256, 1024, 0, stream>>>(li, gi, ls, gs, dist, la0, ga0,
                                          Wcl, bcl, Wll, bll, vl,
                                          Wcg, bcg, Wlg, blg, vg,
                                          Wih, bih, bhh,
                                          (float*)d_ws, (float*)d_out);
}

// Round 8
// 484.327 us; speedup vs baseline: 1.8328x; 1.8328x over previous
//
#include <hip/hip_runtime.h>

#define T_     24
#define LAMDA_ 0.2f

// output layout (flat f32): outs[24,64,256] | cs[64,256] | las[24,64,32] | gas[24,64,256]
#define OFF_CS  393216
#define OFF_LAS 409600
#define OFF_GAS 458752

__device__ __forceinline__ float clamp15(float x){ return fminf(15.f, fmaxf(-15.f, x)); }
__device__ __forceinline__ float rcp_(float x){ return __builtin_amdgcn_rcpf(x); }

typedef float v2f __attribute__((ext_vector_type(2)));
#define PKFMA(a,b,c) __builtin_elementwise_fma((a),(b),(c))

// ---------------------------------------------------------------------------
// R17 = R16 with the compile fix (slred as a proper in-kernel __shared__
// array; the file-scope helper functions were invalid). R16 theory:
//  (1) LSTM fused into phase A tail: slot owns units 2k,2k+1 with their
//      i/g/o rows (u, 512+u, 768+u); after the 8-lane shfl-reduce every
//      lane holds all 6 sums; lanes u8<2 each evaluate one cell inline.
//      Phase B + one barrier + gbuf LDS deleted (5->4 barriers/step).
//  (2) C widened to 768 threads / 16-lane teams (R14/R15-proven code).
//  (3) D s_g inner packed for v_pk_fma_f32 (fp32 peak is the PACKED rate;
//      scalar fma = half issue): z packed in o-pairs, q splatted, rcp
//      scalar -> 24 scalar fma/pair-eval -> 12 pk ops. Fallback = scalar
//      fma (bit-identical, perf-neutral).
// Tripwire: WRITE_SIZE must stay ~3.3MB; >10MB = spill returned.
// ---------------------------------------------------------------------------
__global__ __launch_bounds__(1024, 4) void spat_kernel(
    const float* __restrict__ li,  const float* __restrict__ gi,
    const float* __restrict__ ls,  const float* __restrict__ gs,
    const float* __restrict__ dist,
    const float* __restrict__ la0, const float* __restrict__ ga0,
    const float* __restrict__ Wcl, const float* __restrict__ bcl,
    const float* __restrict__ Wll, const float* __restrict__ bll, const float* __restrict__ vl,
    const float* __restrict__ Wcg, const float* __restrict__ bcg,
    const float* __restrict__ Wlg, const float* __restrict__ blg, const float* __restrict__ vg,
    const float* __restrict__ Wih, const float* __restrict__ bih, const float* __restrict__ bhh,
    float* __restrict__ out)
{
    __shared__ float Eg[6144];               // exp(2*hf_g[o][s]), o<24, s<256
    __shared__ float El[800];                // exp(2*hf_l), idx l*25+o
    __shared__ float outb[6144];             // h outputs  [t][i]
    __shared__ float gasb[6144];             // gas        [t][s]
    __shared__ float lasb[768];              // las        [t][l]
    __shared__ float csb[256];               // c at t=23
    __shared__ float slred[800];             // s_l partials, idx l*25+o
    __shared__ __align__(16) union {
        float wcg[6144];                     // Wcg staging (init only)
        struct {
            float sgred[1024];
            float xv[288];
            float cq[256];
            float slg[32];
        } p;
    } U;
    __shared__ float dstf[256];
    __shared__ float bsum[768];              // bih+bhh: [u]=i, [256+u]=g, [512+u]=o
    __shared__ float bcf[48];                // bll|blg
    __shared__ __align__(16) float4 pl4[12], pg4[12];  // pair coeffs (A0,A1,B1,B2)
    __shared__ float vlf[24], vgf[24], cbuf[2];

    const int b = blockIdx.x, tid = threadIdx.x;
    const int s = tid & 255, ogrp = tid >> 8;

    // ---- small init (before first barrier) ----
    if (tid < 256) dstf[tid] = dist[b*256 + tid];
    if (tid < 24)  { vlf[tid] = vl[tid]; vgf[tid] = vg[tid]; }
    if (tid < 48)  bcf[tid] = (tid < 24) ? bll[tid] : blg[tid - 24];
    if (tid < 768) {
        const int wrow = tid + ((tid >= 256) ? 256 : 0);
        bsum[tid] = bih[wrow] + bhh[wrow];
    }
    if (tid == 0)  { float s1 = 0.f; for (int d = 0; d < 24; d++) s1 += vl[d]; cbuf[0] = s1; }
    if (tid == 1)  { float s1 = 0.f; for (int d = 0; d < 24; d++) s1 += vg[d]; cbuf[1] = s1; }

    // ---- hf_g: thread (s, ogrp) accumulates 6 o's over c<24, j<32 ----
    float acc[6];
#pragma unroll
    for (int i = 0; i < 6; i++) acc[i] = bcg[ogrp*6 + i];

    for (int hc = 0; hc < 3; hc++) {
        for (int k = tid; k < 6144; k += 1024) {
            const int o = k >> 8, r = k & 255;
            U.wcg[k] = Wcg[o*768 + hc*256 + r];
        }
        __syncthreads();
        for (int cc = 0; cc < 8; cc++) {
            const int c = hc*8 + cc;
            const float4* gp = (const float4*)(gs + ((size_t)b*196608 + c*8192 + s*32));
#pragma unroll
            for (int h = 0; h < 2; h++) {            // two 16-float halves of j
                float gv[16];
#pragma unroll
                for (int m = 0; m < 4; m++) {
                    const float4 g = gp[h*4 + m];
                    gv[4*m] = g.x; gv[4*m+1] = g.y; gv[4*m+2] = g.z; gv[4*m+3] = g.w;
                }
#pragma unroll
                for (int i = 0; i < 6; i++) {
                    const float4* wp = (const float4*)(U.wcg + ((ogrp*6 + i)*256 + cc*32)) + h*4;
                    float a = acc[i];
#pragma unroll
                    for (int m = 0; m < 4; m++) {
                        const float4 w = wp[m];
                        a = fmaf(w.x, gv[4*m],   a);
                        a = fmaf(w.y, gv[4*m+1], a);
                        a = fmaf(w.z, gv[4*m+2], a);
                        a = fmaf(w.w, gv[4*m+3], a);
                    }
                    acc[i] = a;
                }
            }
        }
        __syncthreads();
    }
#pragma unroll
    for (int i = 0; i < 6; i++) Eg[(ogrp*6 + i)*256 + s] = __expf(2.f*clamp15(acc[i]));

    // ---- hf_l -> El (transposed: l*25+o) ----
    if (tid < 768) {
        const int o = tid >> 5, l = tid & 31;
        float a = bcl[o];
        for (int c = 0; c < 24; c++)
            a = fmaf(Wcl[o*24 + c], ls[b*768 + c*32 + l], a);
        El[l*25 + o] = __expf(2.f*clamp15(a));
    }

    // ---- x for t=0 (wcg union dead after hc-loop barrier) ----
    if (tid < 288) {
        if (tid < 32) U.p.xv[tid] = la0[b*32 + tid] * li[b*32 + tid];
        else { const int ss = tid - 32; U.p.xv[tid] = ga0[b*256 + ss] * gi[b*256 + ss]; }
    }
    __syncthreads();

    const int u8 = tid & 7, slot = tid >> 3;   // A team layout (128 slots)
    const int u0 = slot*2;                     // slot owns units u0, u0+1

    for (int t = 0; t < T_; t++) {
        // prefetch next-step inputs for the fused x-build (wave0: li, wave1: gi)
        float liN = 0.f;
        float giN0 = 0.f, giN1 = 0.f, giN2 = 0.f, giN3 = 0.f;
        if (t < T_ - 1) {
            if (tid < 32) liN = li[(t+1)*2048 + b*32 + tid];
            else if (tid >= 64 && tid < 128) {
                const int lane = tid - 64;
                giN0 = gi[(t+1)*16384 + b*256 + lane];
                giN1 = gi[(t+1)*16384 + b*256 + lane + 64];
                giN2 = gi[(t+1)*16384 + b*256 + lane + 128];
                giN3 = gi[(t+1)*16384 + b*256 + lane + 192];
            }
        }

        // ---- A: gates GEMV (i/g/o rows of 2 units per slot) + fused LSTM ----
        {
            const float4* xp = (const float4*)U.p.xv;
            float ar0 = 0.f, ar1 = 0.f, ar2 = 0.f, ar3 = 0.f, ar4 = 0.f, ar5 = 0.f;
#pragma unroll 1
            for (int jc = 0; jc < 3; jc++) {
                const float4 x0 = xp[jc*24 + u8];
                const float4 x1 = xp[jc*24 + 8 + u8];
                const float4 x2 = xp[jc*24 + 16 + u8];

#define KROW(WROW, AR) { \
                const float4* wp_ = (const float4*)(Wih + (size_t)(WROW)*288) + jc*24 + u8; \
                const float4 w0_ = wp_[0], w1_ = wp_[8], w2_ = wp_[16]; \
                float a_ = AR; \
                a_ = fmaf(w0_.x,x0.x,a_); a_ = fmaf(w0_.y,x0.y,a_); \
                a_ = fmaf(w0_.z,x0.z,a_); a_ = fmaf(w0_.w,x0.w,a_); \
                a_ = fmaf(w1_.x,x1.x,a_); a_ = fmaf(w1_.y,x1.y,a_); \
                a_ = fmaf(w1_.z,x1.z,a_); a_ = fmaf(w1_.w,x1.w,a_); \
                a_ = fmaf(w2_.x,x2.x,a_); a_ = fmaf(w2_.y,x2.y,a_); \
                a_ = fmaf(w2_.z,x2.z,a_); a_ = fmaf(w2_.w,x2.w,a_); \
                AR = a_; }

                KROW(u0,       ar0) KROW(512 + u0, ar1) KROW(768 + u0, ar2)
                __builtin_amdgcn_sched_barrier(0);
                KROW(u0 + 1,   ar3) KROW(513 + u0, ar4) KROW(769 + u0, ar5)
                __builtin_amdgcn_sched_barrier(0);
#undef KROW
            }
            // 8-lane reduce: all lanes end up with the team sums
            ar0 += __shfl_xor(ar0, 1); ar0 += __shfl_xor(ar0, 2); ar0 += __shfl_xor(ar0, 4);
            ar1 += __shfl_xor(ar1, 1); ar1 += __shfl_xor(ar1, 2); ar1 += __shfl_xor(ar1, 4);
            ar2 += __shfl_xor(ar2, 1); ar2 += __shfl_xor(ar2, 2); ar2 += __shfl_xor(ar2, 4);
            ar3 += __shfl_xor(ar3, 1); ar3 += __shfl_xor(ar3, 2); ar3 += __shfl_xor(ar3, 4);
            ar4 += __shfl_xor(ar4, 1); ar4 += __shfl_xor(ar4, 2); ar4 += __shfl_xor(ar4, 4);
            ar5 += __shfl_xor(ar5, 1); ar5 += __shfl_xor(ar5, 2); ar5 += __shfl_xor(ar5, 4);
            if (u8 < 2) {                     // lane0 -> cell u0, lane1 -> cell u0+1
                const int uu = u0 + u8;
                const float ig = (u8 ? ar3 : ar0) + bsum[uu];
                const float gg = (u8 ? ar4 : ar1) + bsum[256 + uu];
                const float ot = (u8 ? ar5 : ar2) + bsum[512 + uu];
                const float sig_i = rcp_(1.f + __expf(-ig));
                const float th_g  = 1.f - 2.f*rcp_(1.f + __expf(2.f*clamp15(gg)));
                const float c     = sig_i * th_g;
                const float sig_o = rcp_(1.f + __expf(-ot));
                const float th_c  = 1.f - 2.f*rcp_(1.f + __expf(2.f*c));
                const float h     = sig_o * th_c;
                U.p.cq[uu] = c;
                outb[t*256 + uu] = h;
                if (t == T_ - 1) csb[uu] = c;
            }
        }
        __syncthreads();                              // #1: cq/outb ready

        // ---- C: 48 dots x 16-lane teams; F = exp(2y); pair coeffs ----
        if (tid < 768) {
            const int dot = tid >> 4, l16 = tid & 15;
            const float* Wr = (dot < 24) ? (Wll + dot*256) : (Wlg + (dot - 24)*256);
            const float4* wp = (const float4*)Wr + l16*4;
            const float4* cp = (const float4*)U.p.cq + l16*4;
            float a0 = 0.f, a1 = 0.f;
#pragma unroll
            for (int m = 0; m < 4; m += 2) {
                const float4 w0 = wp[m],   c0 = cp[m];
                const float4 w1 = wp[m+1], c1 = cp[m+1];
                a0 = fmaf(w0.x,c0.x,a0); a0 = fmaf(w0.y,c0.y,a0);
                a0 = fmaf(w0.z,c0.z,a0); a0 = fmaf(w0.w,c0.w,a0);
                a1 = fmaf(w1.x,c1.x,a1); a1 = fmaf(w1.y,c1.y,a1);
                a1 = fmaf(w1.z,c1.z,a1); a1 = fmaf(w1.w,c1.w,a1);
            }
            float a = a0 + a1;
            a += __shfl_xor(a, 1); a += __shfl_xor(a, 2);
            a += __shfl_xor(a, 4); a += __shfl_xor(a, 8);
            const float F  = __expf(2.f*clamp15(a + bcf[dot]));
            const float v  = (dot < 24) ? vlf[dot] : vgf[dot - 24];
            const float Fo = __shfl_xor(F, 16);        // partner team (dot^1)
            const float vo = (dot < 24) ? vlf[dot ^ 1] : vgf[(dot ^ 1) - 24];
            if ((tid & 31) == 0) {                     // lane 0 of even dot
                const float A0 = v + vo;
                const float A1 = fmaf(v, Fo, vo * F);
                const float B1 = F + Fo;
                const float B2 = F * Fo;
                const int P2 = dot >> 1;               // 0..23
                if (P2 < 12) pl4[P2]      = make_float4(A0, A1, B1, B2);
                else         pg4[P2 - 12] = make_float4(A0, A1, B1, B2);
            }
        }
        __syncthreads();                              // #2

        // ---- D: s_g partials (all threads, packed v_pk_fma over o-pairs)
        //      + s_l partials (tid<768, scalar) ----
        {
            float z[6];
#pragma unroll
            for (int i = 0; i < 6; i++) z[i] = Eg[(ogrp*6 + i)*256 + s];
            const v2f zv0 = {z[0], z[1]}, zv1 = {z[2], z[3]}, zv2 = {z[4], z[5]};
            const v2f z2v0 = zv0*zv0, z2v1 = zv1*zv1, z2v2 = zv2*zv2;
            const v2f one2 = {1.f, 1.f};
            v2f acc2 = {0.f, 0.f};
#pragma unroll 4
            for (int p = 0; p < 12; p++) {
                const float4 q = pg4[p];
                const v2f qx = {q.x, q.x}, qy = {q.y, q.y};
                const v2f qz = {q.z, q.z}, qw = {q.w, q.w};
                const v2f n0 = PKFMA(zv0, qy, qx);
                const v2f n1 = PKFMA(zv1, qy, qx);
                const v2f n2 = PKFMA(zv2, qy, qx);
                const v2f d0 = PKFMA(z2v0, qw, PKFMA(zv0, qz, one2));
                const v2f d1 = PKFMA(z2v1, qw, PKFMA(zv1, qz, one2));
                const v2f d2 = PKFMA(z2v2, qw, PKFMA(zv2, qz, one2));
                const v2f r0 = {rcp_(d0.x), rcp_(d0.y)};
                const v2f r1 = {rcp_(d1.x), rcp_(d1.y)};
                const v2f r2 = {rcp_(d2.x), rcp_(d2.y)};
                acc2 = PKFMA(n0, r0, acc2);
                acc2 = PKFMA(n1, r1, acc2);
                acc2 = PKFMA(n2, r2, acc2);
            }
            U.p.sgred[tid] = acc2.x + acc2.y;
        }
        if (tid < 768) {
            const int l = tid / 24, o = tid - l*24;
            const float E  = El[l*25 + o];
            const float E2 = E*E;
            float b0 = 0.f, b1 = 0.f;
#pragma unroll 4
            for (int p = 0; p < 12; p += 2) {
                const float4 q0 = pl4[p], q1 = pl4[p+1];
                const float n0 = fmaf(E, q0.y, q0.x);
                const float d0 = fmaf(E2, q0.w, fmaf(E, q0.z, 1.f));
                const float n1 = fmaf(E, q1.y, q1.x);
                const float d1 = fmaf(E2, q1.w, fmaf(E, q1.z, 1.f));
                b0 = fmaf(n0, rcp_(d0), b0);
                b1 = fmaf(n1, rcp_(d1), b1);
            }
            slred[l*25 + o] = b0 + b1;
        }
        __syncthreads();                              // #3

        // ---- E: both softmaxes + next-step x-build (LDS outputs) ----
        if (tid < 32) {                       // wave0: s_l softmax
            float tot = 0.f;
#pragma unroll
            for (int o2 = 0; o2 < 24; o2++) tot += slred[tid*25 + o2];
            const float sv = 24.f*cbuf[0] - 2.f*tot;
            float m = sv;
#pragma unroll
            for (int mk = 16; mk >= 1; mk >>= 1) m = fmaxf(m, __shfl_xor(m, mk));
            const float e = __expf(sv - m);
            float ss = e;
#pragma unroll
            for (int mk = 16; mk >= 1; mk >>= 1) ss += __shfl_xor(ss, mk);
            const float r = e * rcp_(ss);
            lasb[t*32 + tid] = r;
            if (t < T_ - 1) U.p.xv[tid] = r * liN;
        } else if (tid >= 64 && tid < 128) {  // wave1: s_g softmax, 4 s/lane
            const int lane = tid - 64;
            float vv0, vv1, vv2, vv3;
            {
                const float t0 = U.p.sgred[lane]     + U.p.sgred[256+lane]     + U.p.sgred[512+lane]     + U.p.sgred[768+lane];
                const float t1 = U.p.sgred[lane+64]  + U.p.sgred[256+lane+64]  + U.p.sgred[512+lane+64]  + U.p.sgred[768+lane+64];
                const float t2 = U.p.sgred[lane+128] + U.p.sgred[256+lane+128] + U.p.sgred[512+lane+128] + U.p.sgred[768+lane+128];
                const float t3 = U.p.sgred[lane+192] + U.p.sgred[256+lane+192] + U.p.sgred[512+lane+192] + U.p.sgred[768+lane+192];
                vv0 = (1.f-LAMDA_)*(24.f*cbuf[1] - 2.f*t0) + LAMDA_*dstf[lane];
                vv1 = (1.f-LAMDA_)*(24.f*cbuf[1] - 2.f*t1) + LAMDA_*dstf[lane+64];
                vv2 = (1.f-LAMDA_)*(24.f*cbuf[1] - 2.f*t2) + LAMDA_*dstf[lane+128];
                vv3 = (1.f-LAMDA_)*(24.f*cbuf[1] - 2.f*t3) + LAMDA_*dstf[lane+192];
            }
            float m = fmaxf(fmaxf(vv0, vv1), fmaxf(vv2, vv3));
#pragma unroll
            for (int mk = 32; mk >= 1; mk >>= 1) m = fmaxf(m, __shfl_xor(m, mk));
            const float e0 = __expf(vv0 - m), e1 = __expf(vv1 - m);
            const float e2 = __expf(vv2 - m), e3 = __expf(vv3 - m);
            float ss = (e0 + e1) + (e2 + e3);
#pragma unroll
            for (int mk = 32; mk >= 1; mk >>= 1) ss += __shfl_xor(ss, mk);
            const float inv = rcp_(ss);
            const float r0 = e0*inv, r1 = e1*inv, r2 = e2*inv, r3 = e3*inv;
            float* gb = gasb + t*256;
            gb[lane] = r0; gb[lane+64] = r1; gb[lane+128] = r2; gb[lane+192] = r3;
            if (t < T_ - 1) {
                U.p.xv[32+lane]     = r0 * giN0;
                U.p.xv[32+lane+64]  = r1 * giN1;
                U.p.xv[32+lane+128] = r2 * giN2;
                U.p.xv[32+lane+192] = r3 * giN3;
            }
        }
        __syncthreads();                              // #4
    }

    // ---- final flush: LDS output buffers -> global, coalesced ----
    for (int k = tid; k < 6144; k += 1024) {
        const int tt = k >> 8, ii = k & 255;
        out[tt*16384 + b*256 + ii]           = outb[k];
        out[OFF_GAS + tt*16384 + b*256 + ii] = gasb[k];
    }
    if (tid < 768) out[OFF_LAS + (tid >> 5)*2048 + b*32 + (tid & 31)] = lasb[tid];
    if (tid < 256) out[OFF_CS + b*256 + tid] = csb[tid];
}

extern "C" void kernel_launch(void* const* d_in, const int* in_sizes, int n_in,
                              void* d_out, int out_size, void* d_ws, size_t ws_size,
                              hipStream_t stream)
{
    const float* li   = (const float*)d_in[0];
    const float* gi   = (const float*)d_in[1];
    const float* ls   = (const float*)d_in[2];
    const float* gs   = (const float*)d_in[3];
    const float* dist = (const float*)d_in[4];
    const float* la0  = (const float*)d_in[5];
    const float* ga0  = (const float*)d_in[6];
    const float* Wcl  = (const float*)d_in[7];
    const float* bcl  = (const float*)d_in[8];
    const float* Wll  = (const float*)d_in[9];
    const float* bll  = (const float*)d_in[10];
    const float* vl   = (const float*)d_in[11];
    const float* Wcg  = (const float*)d_in[12];
    const float* bcg  = (const float*)d_in[13];
    const float* Wlg  = (const float*)d_in[14];
    const float* blg  = (const float*)d_in[15];
    const float* vg   = (const float*)d_in[16];
    const float* Wih  = (const float*)d_in[17];
    const float* bih  = (const float*)d_in[18];
    const float* bhh  = (const float*)d_in[19];

    spat_kernel<<<64, 1024, 0, stream>>>(li, gi, ls, gs, dist, la0, ga0,
                                         Wcl, bcl, Wll, bll, vl,
                                         Wcg, bcg, Wlg, blg, vg,
                                         Wih, bih, bhh, (float*)d_out);
}

// Round 9
// 479.434 us; speedup vs baseline: 1.8515x; 1.0102x over previous
//
#include <hip/hip_runtime.h>

#define T_     24
#define LAMDA_ 0.2f

// output layout (flat f32): outs[24,64,256] | cs[64,256] | las[24,64,32] | gas[24,64,256]
#define OFF_CS  393216
#define OFF_LAS 409600
#define OFF_GAS 458752

__device__ __forceinline__ float clamp15(float x){ return fminf(15.f, fmaxf(-15.f, x)); }
__device__ __forceinline__ float rcp_(float x){ return __builtin_amdgcn_rcpf(x); }

typedef float v2f __attribute__((ext_vector_type(2)));
typedef float v4f __attribute__((ext_vector_type(4)));
#define PKFMA(a,b,c) __builtin_elementwise_fma((a),(b),(c))

// ---------------------------------------------------------------------------
// R18: R17 = 394us steady (B fused into A, 4 barriers, packed D). This round:
//  (1) #pragma unroll 1 on t/hc/cc loops: pins the hot body small so it stays
//      I$-resident (guard against full-unroll code bloat -- a hidden tax that
//      never shows in VALUBusy). Zero cost if unrolling wasn't happening.
//  (2) init conv packed: 4608 fma/thread -> 2304 v_pk_fma_f32 via v2f accs
//      and .xy/.zw swizzles of b128 quads (contiguous VGPR pairs, no moves).
//      Init issue ~15us -> ~9us.
//  (3) phase A GEMV packed: 216 fma -> 108 pk + 6 adds.
//  (4) phase C dot packed: 32 fma -> 16 pk.
//  (5) D/E unchanged (D already packed; pair-rational numerics proven).
// Tripwire: WRITE_SIZE must stay ~3.3MB; >10MB = spill returned.
// ---------------------------------------------------------------------------
__global__ __launch_bounds__(1024, 4) void spat_kernel(
    const float* __restrict__ li,  const float* __restrict__ gi,
    const float* __restrict__ ls,  const float* __restrict__ gs,
    const float* __restrict__ dist,
    const float* __restrict__ la0, const float* __restrict__ ga0,
    const float* __restrict__ Wcl, const float* __restrict__ bcl,
    const float* __restrict__ Wll, const float* __restrict__ bll, const float* __restrict__ vl,
    const float* __restrict__ Wcg, const float* __restrict__ bcg,
    const float* __restrict__ Wlg, const float* __restrict__ blg, const float* __restrict__ vg,
    const float* __restrict__ Wih, const float* __restrict__ bih, const float* __restrict__ bhh,
    float* __restrict__ out)
{
    __shared__ float Eg[6144];               // exp(2*hf_g[o][s]), o<24, s<256
    __shared__ float El[800];                // exp(2*hf_l), idx l*25+o
    __shared__ float outb[6144];             // h outputs  [t][i]
    __shared__ float gasb[6144];             // gas        [t][s]
    __shared__ float lasb[768];              // las        [t][l]
    __shared__ float csb[256];               // c at t=23
    __shared__ float slred[800];             // s_l partials, idx l*25+o
    __shared__ __align__(16) union {
        float wcg[6144];                     // Wcg staging (init only)
        struct {
            float sgred[1024];
            float xv[288];
            float cq[256];
            float slg[32];
        } p;
    } U;
    __shared__ float dstf[256];
    __shared__ float bsum[768];              // bih+bhh: [u]=i, [256+u]=g, [512+u]=o
    __shared__ float bcf[48];                // bll|blg
    __shared__ __align__(16) float4 pl4[12], pg4[12];  // pair coeffs (A0,A1,B1,B2)
    __shared__ float vlf[24], vgf[24], cbuf[2];

    const int b = blockIdx.x, tid = threadIdx.x;
    const int s = tid & 255, ogrp = tid >> 8;

    // ---- small init (before first barrier) ----
    if (tid < 256) dstf[tid] = dist[b*256 + tid];
    if (tid < 24)  { vlf[tid] = vl[tid]; vgf[tid] = vg[tid]; }
    if (tid < 48)  bcf[tid] = (tid < 24) ? bll[tid] : blg[tid - 24];
    if (tid < 768) {
        const int wrow = tid + ((tid >= 256) ? 256 : 0);
        bsum[tid] = bih[wrow] + bhh[wrow];
    }
    if (tid == 0)  { float s1 = 0.f; for (int d = 0; d < 24; d++) s1 += vl[d]; cbuf[0] = s1; }
    if (tid == 1)  { float s1 = 0.f; for (int d = 0; d < 24; d++) s1 += vg[d]; cbuf[1] = s1; }

    // ---- hf_g: thread (s, ogrp) accumulates 6 o's over c<24, j<32 (packed) ----
    v2f acc2[6];
#pragma unroll
    for (int i = 0; i < 6; i++) acc2[i] = (v2f){bcg[ogrp*6 + i], 0.f};

#pragma unroll 1
    for (int hc = 0; hc < 3; hc++) {
        for (int k = tid; k < 6144; k += 1024) {
            const int o = k >> 8, r = k & 255;
            U.wcg[k] = Wcg[o*768 + hc*256 + r];
        }
        __syncthreads();
#pragma unroll 1
        for (int cc = 0; cc < 8; cc++) {
            const int c = hc*8 + cc;
            const v4f* gp = (const v4f*)(gs + ((size_t)b*196608 + c*8192 + s*32));
#pragma unroll
            for (int h = 0; h < 2; h++) {            // two 16-float halves of j
                const v4f g0 = gp[h*4 + 0], g1 = gp[h*4 + 1];
                const v4f g2 = gp[h*4 + 2], g3 = gp[h*4 + 3];
#pragma unroll
                for (int i = 0; i < 6; i++) {
                    const v4f* wp = (const v4f*)(U.wcg + ((ogrp*6 + i)*256 + cc*32)) + h*4;
                    const v4f w0 = wp[0], w1 = wp[1], w2 = wp[2], w3 = wp[3];
                    v2f a = acc2[i];
                    a = PKFMA(w0.xy, g0.xy, a); a = PKFMA(w0.zw, g0.zw, a);
                    a = PKFMA(w1.xy, g1.xy, a); a = PKFMA(w1.zw, g1.zw, a);
                    a = PKFMA(w2.xy, g2.xy, a); a = PKFMA(w2.zw, g2.zw, a);
                    a = PKFMA(w3.xy, g3.xy, a); a = PKFMA(w3.zw, g3.zw, a);
                    acc2[i] = a;
                }
            }
        }
        __syncthreads();
    }
#pragma unroll
    for (int i = 0; i < 6; i++)
        Eg[(ogrp*6 + i)*256 + s] = __expf(2.f*clamp15(acc2[i].x + acc2[i].y));

    // ---- hf_l -> El (transposed: l*25+o) ----
    if (tid < 768) {
        const int o = tid >> 5, l = tid & 31;
        float a = bcl[o];
        for (int c = 0; c < 24; c++)
            a = fmaf(Wcl[o*24 + c], ls[b*768 + c*32 + l], a);
        El[l*25 + o] = __expf(2.f*clamp15(a));
    }

    // ---- x for t=0 (wcg union dead after hc-loop barrier) ----
    if (tid < 288) {
        if (tid < 32) U.p.xv[tid] = la0[b*32 + tid] * li[b*32 + tid];
        else { const int ss = tid - 32; U.p.xv[tid] = ga0[b*256 + ss] * gi[b*256 + ss]; }
    }
    __syncthreads();

    const int u8 = tid & 7, slot = tid >> 3;   // A team layout (128 slots)
    const int u0 = slot*2;                     // slot owns units u0, u0+1

#pragma unroll 1
    for (int t = 0; t < T_; t++) {
        // prefetch next-step inputs for the fused x-build (wave0: li, wave1: gi)
        float liN = 0.f;
        float giN0 = 0.f, giN1 = 0.f, giN2 = 0.f, giN3 = 0.f;
        if (t < T_ - 1) {
            if (tid < 32) liN = li[(t+1)*2048 + b*32 + tid];
            else if (tid >= 64 && tid < 128) {
                const int lane = tid - 64;
                giN0 = gi[(t+1)*16384 + b*256 + lane];
                giN1 = gi[(t+1)*16384 + b*256 + lane + 64];
                giN2 = gi[(t+1)*16384 + b*256 + lane + 128];
                giN3 = gi[(t+1)*16384 + b*256 + lane + 192];
            }
        }

        // ---- A: gates GEMV (i/g/o rows of 2 units per slot), packed,
        //      fused LSTM tail ----
        {
            const v4f* xp = (const v4f*)U.p.xv;
            v2f br0 = {0.f,0.f}, br1 = {0.f,0.f}, br2 = {0.f,0.f};
            v2f br3 = {0.f,0.f}, br4 = {0.f,0.f}, br5 = {0.f,0.f};
#pragma unroll 1
            for (int jc = 0; jc < 3; jc++) {
                const v4f x0 = xp[jc*24 + u8];
                const v4f x1 = xp[jc*24 + 8 + u8];
                const v4f x2 = xp[jc*24 + 16 + u8];

#define KROW(WROW, AR) { \
                const v4f* wp_ = (const v4f*)(Wih + (size_t)(WROW)*288) + jc*24 + u8; \
                const v4f w0_ = wp_[0], w1_ = wp_[8], w2_ = wp_[16]; \
                v2f a_ = AR; \
                a_ = PKFMA(w0_.xy, x0.xy, a_); a_ = PKFMA(w0_.zw, x0.zw, a_); \
                a_ = PKFMA(w1_.xy, x1.xy, a_); a_ = PKFMA(w1_.zw, x1.zw, a_); \
                a_ = PKFMA(w2_.xy, x2.xy, a_); a_ = PKFMA(w2_.zw, x2.zw, a_); \
                AR = a_; }

                KROW(u0,       br0) KROW(512 + u0, br1) KROW(768 + u0, br2)
                __builtin_amdgcn_sched_barrier(0);
                KROW(u0 + 1,   br3) KROW(513 + u0, br4) KROW(769 + u0, br5)
                __builtin_amdgcn_sched_barrier(0);
#undef KROW
            }
            float ar0 = br0.x + br0.y, ar1 = br1.x + br1.y, ar2 = br2.x + br2.y;
            float ar3 = br3.x + br3.y, ar4 = br4.x + br4.y, ar5 = br5.x + br5.y;
            // 8-lane reduce: all lanes end up with the team sums
            ar0 += __shfl_xor(ar0, 1); ar0 += __shfl_xor(ar0, 2); ar0 += __shfl_xor(ar0, 4);
            ar1 += __shfl_xor(ar1, 1); ar1 += __shfl_xor(ar1, 2); ar1 += __shfl_xor(ar1, 4);
            ar2 += __shfl_xor(ar2, 1); ar2 += __shfl_xor(ar2, 2); ar2 += __shfl_xor(ar2, 4);
            ar3 += __shfl_xor(ar3, 1); ar3 += __shfl_xor(ar3, 2); ar3 += __shfl_xor(ar3, 4);
            ar4 += __shfl_xor(ar4, 1); ar4 += __shfl_xor(ar4, 2); ar4 += __shfl_xor(ar4, 4);
            ar5 += __shfl_xor(ar5, 1); ar5 += __shfl_xor(ar5, 2); ar5 += __shfl_xor(ar5, 4);
            if (u8 < 2) {                     // lane0 -> cell u0, lane1 -> cell u0+1
                const int uu = u0 + u8;
                const float ig = (u8 ? ar3 : ar0) + bsum[uu];
                const float gg = (u8 ? ar4 : ar1) + bsum[256 + uu];
                const float ot = (u8 ? ar5 : ar2) + bsum[512 + uu];
                const float sig_i = rcp_(1.f + __expf(-ig));
                const float th_g  = 1.f - 2.f*rcp_(1.f + __expf(2.f*clamp15(gg)));
                const float c     = sig_i * th_g;
                const float sig_o = rcp_(1.f + __expf(-ot));
                const float th_c  = 1.f - 2.f*rcp_(1.f + __expf(2.f*c));
                const float h     = sig_o * th_c;
                U.p.cq[uu] = c;
                outb[t*256 + uu] = h;
                if (t == T_ - 1) csb[uu] = c;
            }
        }
        __syncthreads();                              // #1: cq/outb ready

        // ---- C: 48 dots x 16-lane teams (packed); F = exp(2y); pair coeffs ----
        if (tid < 768) {
            const int dot = tid >> 4, l16 = tid & 15;
            const float* Wr = (dot < 24) ? (Wll + dot*256) : (Wlg + (dot - 24)*256);
            const v4f* wp = (const v4f*)Wr + l16*4;
            const v4f* cp = (const v4f*)U.p.cq + l16*4;
            v2f a2 = {0.f, 0.f};
#pragma unroll
            for (int m = 0; m < 4; m++) {
                const v4f w0 = wp[m], c0 = cp[m];
                a2 = PKFMA(w0.xy, c0.xy, a2);
                a2 = PKFMA(w0.zw, c0.zw, a2);
            }
            float a = a2.x + a2.y;
            a += __shfl_xor(a, 1); a += __shfl_xor(a, 2);
            a += __shfl_xor(a, 4); a += __shfl_xor(a, 8);
            const float F  = __expf(2.f*clamp15(a + bcf[dot]));
            const float v  = (dot < 24) ? vlf[dot] : vgf[dot - 24];
            const float Fo = __shfl_xor(F, 16);        // partner team (dot^1)
            const float vo = (dot < 24) ? vlf[dot ^ 1] : vgf[(dot ^ 1) - 24];
            if ((tid & 31) == 0) {                     // lane 0 of even dot
                const float A0 = v + vo;
                const float A1 = fmaf(v, Fo, vo * F);
                const float B1 = F + Fo;
                const float B2 = F * Fo;
                const int P2 = dot >> 1;               // 0..23
                if (P2 < 12) pl4[P2]      = make_float4(A0, A1, B1, B2);
                else         pg4[P2 - 12] = make_float4(A0, A1, B1, B2);
            }
        }
        __syncthreads();                              // #2

        // ---- D: s_g partials (all threads, packed v_pk_fma over o-pairs)
        //      + s_l partials (tid<768, scalar) ----
        {
            float z[6];
#pragma unroll
            for (int i = 0; i < 6; i++) z[i] = Eg[(ogrp*6 + i)*256 + s];
            const v2f zv0 = {z[0], z[1]}, zv1 = {z[2], z[3]}, zv2 = {z[4], z[5]};
            const v2f z2v0 = zv0*zv0, z2v1 = zv1*zv1, z2v2 = zv2*zv2;
            const v2f one2 = {1.f, 1.f};
            v2f acc2d = {0.f, 0.f};
#pragma unroll 4
            for (int p = 0; p < 12; p++) {
                const float4 q = pg4[p];
                const v2f qx = {q.x, q.x}, qy = {q.y, q.y};
                const v2f qz = {q.z, q.z}, qw = {q.w, q.w};
                const v2f n0 = PKFMA(zv0, qy, qx);
                const v2f n1 = PKFMA(zv1, qy, qx);
                const v2f n2 = PKFMA(zv2, qy, qx);
                const v2f d0 = PKFMA(z2v0, qw, PKFMA(zv0, qz, one2));
                const v2f d1 = PKFMA(z2v1, qw, PKFMA(zv1, qz, one2));
                const v2f d2 = PKFMA(z2v2, qw, PKFMA(zv2, qz, one2));
                const v2f r0 = {rcp_(d0.x), rcp_(d0.y)};
                const v2f r1 = {rcp_(d1.x), rcp_(d1.y)};
                const v2f r2 = {rcp_(d2.x), rcp_(d2.y)};
                acc2d = PKFMA(n0, r0, acc2d);
                acc2d = PKFMA(n1, r1, acc2d);
                acc2d = PKFMA(n2, r2, acc2d);
            }
            U.p.sgred[tid] = acc2d.x + acc2d.y;
        }
        if (tid < 768) {
            const int l = tid / 24, o = tid - l*24;
            const float E  = El[l*25 + o];
            const float E2 = E*E;
            float b0 = 0.f, b1 = 0.f;
#pragma unroll 4
            for (int p = 0; p < 12; p += 2) {
                const float4 q0 = pl4[p], q1 = pl4[p+1];
                const float n0 = fmaf(E, q0.y, q0.x);
                const float d0 = fmaf(E2, q0.w, fmaf(E, q0.z, 1.f));
                const float n1 = fmaf(E, q1.y, q1.x);
                const float d1 = fmaf(E2, q1.w, fmaf(E, q1.z, 1.f));
                b0 = fmaf(n0, rcp_(d0), b0);
                b1 = fmaf(n1, rcp_(d1), b1);
            }
            slred[l*25 + o] = b0 + b1;
        }
        __syncthreads();                              // #3

        // ---- E: both softmaxes + next-step x-build (LDS outputs) ----
        if (tid < 32) {                       // wave0: s_l softmax
            float tot = 0.f;
#pragma unroll
            for (int o2 = 0; o2 < 24; o2++) tot += slred[tid*25 + o2];
            const float sv = 24.f*cbuf[0] - 2.f*tot;
            float m = sv;
#pragma unroll
            for (int mk = 16; mk >= 1; mk >>= 1) m = fmaxf(m, __shfl_xor(m, mk));
            const float e = __expf(sv - m);
            float ss = e;
#pragma unroll
            for (int mk = 16; mk >= 1; mk >>= 1) ss += __shfl_xor(ss, mk);
            const float r = e * rcp_(ss);
            lasb[t*32 + tid] = r;
            if (t < T_ - 1) U.p.xv[tid] = r * liN;
        } else if (tid >= 64 && tid < 128) {  // wave1: s_g softmax, 4 s/lane
            const int lane = tid - 64;
            float vv0, vv1, vv2, vv3;
            {
                const float t0 = U.p.sgred[lane]     + U.p.sgred[256+lane]     + U.p.sgred[512+lane]     + U.p.sgred[768+lane];
                const float t1 = U.p.sgred[lane+64]  + U.p.sgred[256+lane+64]  + U.p.sgred[512+lane+64]  + U.p.sgred[768+lane+64];
                const float t2 = U.p.sgred[lane+128] + U.p.sgred[256+lane+128] + U.p.sgred[512+lane+128] + U.p.sgred[768+lane+128];
                const float t3 = U.p.sgred[lane+192] + U.p.sgred[256+lane+192] + U.p.sgred[512+lane+192] + U.p.sgred[768+lane+192];
                vv0 = (1.f-LAMDA_)*(24.f*cbuf[1] - 2.f*t0) + LAMDA_*dstf[lane];
                vv1 = (1.f-LAMDA_)*(24.f*cbuf[1] - 2.f*t1) + LAMDA_*dstf[lane+64];
                vv2 = (1.f-LAMDA_)*(24.f*cbuf[1] - 2.f*t2) + LAMDA_*dstf[lane+128];
                vv3 = (1.f-LAMDA_)*(24.f*cbuf[1] - 2.f*t3) + LAMDA_*dstf[lane+192];
            }
            float m = fmaxf(fmaxf(vv0, vv1), fmaxf(vv2, vv3));
#pragma unroll
            for (int mk = 32; mk >= 1; mk >>= 1) m = fmaxf(m, __shfl_xor(m, mk));
            const float e0 = __expf(vv0 - m), e1 = __expf(vv1 - m);
            const float e2 = __expf(vv2 - m), e3 = __expf(vv3 - m);
            float ss = (e0 + e1) + (e2 + e3);
#pragma unroll
            for (int mk = 32; mk >= 1; mk >>= 1) ss += __shfl_xor(ss, mk);
            const float inv = rcp_(ss);
            const float r0 = e0*inv, r1 = e1*inv, r2 = e2*inv, r3 = e3*inv;
            float* gb = gasb + t*256;
            gb[lane] = r0; gb[lane+64] = r1; gb[lane+128] = r2; gb[lane+192] = r3;
            if (t < T_ - 1) {
                U.p.xv[32+lane]     = r0 * giN0;
                U.p.xv[32+lane+64]  = r1 * giN1;
                U.p.xv[32+lane+128] = r2 * giN2;
                U.p.xv[32+lane+192] = r3 * giN3;
            }
        }
        __syncthreads();                              // #4
    }

    // ---- final flush: LDS output buffers -> global, coalesced ----
    for (int k = tid; k < 6144; k += 1024) {
        const int tt = k >> 8, ii = k & 255;
        out[tt*16384 + b*256 + ii]           = outb[k];
        out[OFF_GAS + tt*16384 + b*256 + ii] = gasb[k];
    }
    if (tid < 768) out[OFF_LAS + (tid >> 5)*2048 + b*32 + (tid & 31)] = lasb[tid];
    if (tid < 256) out[OFF_CS + b*256 + tid] = csb[tid];
}

extern "C" void kernel_launch(void* const* d_in, const int* in_sizes, int n_in,
                              void* d_out, int out_size, void* d_ws, size_t ws_size,
                              hipStream_t stream)
{
    const float* li   = (const float*)d_in[0];
    const float* gi   = (const float*)d_in[1];
    const float* ls   = (const float*)d_in[2];
    const float* gs   = (const float*)d_in[3];
    const float* dist = (const float*)d_in[4];
    const float* la0  = (const float*)d_in[5];
    const float* ga0  = (const float*)d_in[6];
    const float* Wcl  = (const float*)d_in[7];
    const float* bcl  = (const float*)d_in[8];
    const float* Wll  = (const float*)d_in[9];
    const float* bll  = (const float*)d_in[10];
    const float* vl   = (const float*)d_in[11];
    const float* Wcg  = (const float*)d_in[12];
    const float* bcg  = (const float*)d_in[13];
    const float* Wlg  = (const float*)d_in[14];
    const float* blg  = (const float*)d_in[15];
    const float* vg   = (const float*)d_in[16];
    const float* Wih  = (const float*)d_in[17];
    const float* bih  = (const float*)d_in[18];
    const float* bhh  = (const float*)d_in[19];

    spat_kernel<<<64, 1024, 0, stream>>>(li, gi, ls, gs, dist, la0, ga0,
                                         Wcl, bcl, Wll, bll, vl,
                                         Wcg, bcg, Wlg, blg, vg,
                                         Wih, bih, bhh, (float*)d_out);
}